// Round 14
// baseline (410.060 us; speedup 1.0000x reference)
//
#include <hip/hip_runtime.h>

#define BN 200
#define VN 64
#define HIDD 64
#define FINN 32
#define NSW 10
#define EC 63
#define MNE 73
#define NE_MAX 256

typedef unsigned short u16;
typedef unsigned int u32;
typedef __attribute__((ext_vector_type(8))) short bf16x8;
typedef __attribute__((ext_vector_type(4))) float f32x4;

__device__ __forceinline__ float bfu(u16 u) { return __uint_as_float(((u32)u) << 16); }
__device__ __forceinline__ u16 f2bf(float f) {
    u32 x = __float_as_uint(f);
    u32 r = x + 0x7fffu + ((x >> 16) & 1u);
    return (u16)(r >> 16);
}
__device__ __forceinline__ float cvtv(const void* p, int i, int fl) {
    return fl ? bfu(((const u16*)p)[i]) : ((const float*)p)[i];
}
__device__ __forceinline__ float rlane(float v, int h) {
    return __uint_as_float(__builtin_amdgcn_readlane(__float_as_uint(v), h));
}

__device__ __forceinline__ float ln_relu64(float e) {
    float s1 = e, s2 = e * e;
#pragma unroll
    for (int m = 1; m < 64; m <<= 1) {
        s1 += __shfl_xor(s1, m);
        s2 += __shfl_xor(s2, m);
    }
    float mean = s1 * 0.015625f;
    float var = fmaxf(s2 * 0.015625f - mean * mean, 0.f);
    return fmaxf((e - mean) * rsqrtf(var + 1e-5f), 0.f);
}

// xrow distributed over lanes; wcol[h] = W[h][lane] in regs; 4-acc to cut dep chain
__device__ __forceinline__ float mv64(float xrow, const float* wcol) {
    float a0 = 0.f, a1 = 0.f, a2 = 0.f, a3 = 0.f;
#pragma unroll
    for (int h = 0; h < 64; h += 4) {
        a0 += rlane(xrow, h) * wcol[h];
        a1 += rlane(xrow, h + 1) * wcol[h + 1];
        a2 += rlane(xrow, h + 2) * wcol[h + 2];
        a3 += rlane(xrow, h + 3) * wcol[h + 3];
    }
    return (a0 + a1) + (a2 + a3);
}
__device__ __forceinline__ float mv32(float xrow, const float* wcol) {
    float a0 = 0.f, a1 = 0.f, a2 = 0.f, a3 = 0.f;
#pragma unroll
    for (int h = 0; h < 32; h += 4) {
        a0 += rlane(xrow, h) * wcol[h];
        a1 += rlane(xrow, h + 1) * wcol[h + 1];
        a2 += rlane(xrow, h + 2) * wcol[h + 2];
        a3 += rlane(xrow, h + 3) * wcol[h + 3];
    }
    return (a0 + a1) + (a2 + a3);
}

// split 8 consecutive floats into hi/lo bf16 fragments
__device__ __forceinline__ void split8(const float* base, bf16x8* hi, bf16x8* lo) {
    union { bf16x8 v; u16 s[8]; } uh, ul;
#pragma unroll
    for (int j = 0; j < 8; j++) {
        float f = base[j];
        u16 h = f2bf(f);
        uh.s[j] = h;
        ul.s[j] = f2bf(f - bfu(h));
    }
    *hi = uh.v;
    *lo = ul.v;
}

struct CvtArgs {
    const void* src[21];
    int cnt[21];
};

// ======== prep: block 0 = CSR/ews/dinv/sw_eidx/inc-lists; blocks 1-64 = head pack; rest = convert ========
__global__ __launch_bounds__(256) void k_prep(CvtArgs ca, const int* __restrict__ eA,
                                              const int* __restrict__ eS,
                                              float* __restrict__ pool,
                                              u16* __restrict__ c1h, u16* __restrict__ c1l,
                                              u16* __restrict__ c2h, u16* __restrict__ c2l,
                                              u16* __restrict__ s1h, u16* __restrict__ s1l,
                                              u16* __restrict__ s2h, u16* __restrict__ s2l,
                                              float* __restrict__ ews, float* __restrict__ dinv,
                                              int* __restrict__ row_ptr, int* __restrict__ colp,
                                              int* __restrict__ sw_eidx,
                                              float* __restrict__ dinvD, int* __restrict__ incCnt,
                                              int* __restrict__ incM, int cvt_total) {
    int t = threadIdx.x;
    int fl = (((const u16*)ca.src[1])[1] == 0x3F80) ? 1 : 0;
    if (blockIdx.x == 0) {
        __shared__ float connL[4096];
        __shared__ int degL[64], rpS[65];
        const void* A = ca.src[1];
        const void* S = ca.src[2];
        for (int i = t; i < 4096; i += 256)
            connL[i] = fminf(cvtv(A, i, fl) + cvtv(S, i, fl), 1.f);
        if (t < 128) {
            int j = t >> 6, k = t & 63;
            float a = 0.f;
            for (int h = 0; h < FINN; h++)
                a += cvtv(ca.src[3], j * FINN + h, fl) * cvtv(ca.src[4], h * 64 + k, fl);
            ews[(j << 6) + k] = a;
        }
        __syncthreads();
        if (t < 64) {
            int d = 0;
            for (int w = 0; w < 64; w++) if (connL[t * 64 + w] != 0.f) d++;
            degL[t] = d;
            dinv[t] = 1.f / fmaxf((float)d, 1.f);
        }
        __syncthreads();
        if (t == 0) {
            int c = 0;
            for (int v = 0; v < 64; v++) { rpS[v] = c; c += degL[v]; }
            rpS[64] = c;
            for (int v = 0; v <= 64; v++) row_ptr[v] = rpS[v];
        }
        __syncthreads();
        if (t < 64) {
            int pos = rpS[t];
            for (int w = 0; w < 64; w++)
                if (connL[t * 64 + w] != 0.f)
                    colp[pos++] = w | ((cvtv(S, t * 64 + w, fl) != 0.f) ? 256 : 0);
        }
        __syncthreads();
        if (t < NSW) {
            int si = eS[t], sj = eS[NSW + t];
            int idx = 0;
            for (int e = rpS[si]; e < rpS[si + 1]; e++)
                if ((colp[e] & 255) == sj) idx = e;
            sw_eidx[t] = idx;
        }
        if (t < 64) {
            dinvD[t] = cvtv(ca.src[18], t * 64 + t, fl);
            int cnt = 0;
            for (int m = 0; m < MNE; m++) {
                int par = (m < EC) ? eA[m] : eS[m - EC];
                int chi = (m < EC) ? eA[EC + m] : eS[NSW + (m - EC)];
                if (par == t && cnt < 8) incM[t * 8 + cnt++] = (m << 1);
                if (chi == t && cnt < 8) incM[t * 8 + cnt++] = (m << 1) | 1;
            }
            incCnt[t] = cnt;
        }
    } else if (blockIdx.x <= 64) {
        const int TOT = 36864 + 3072 + 65536 + 4096;
        for (int i = (blockIdx.x - 1) * 256 + t; i < TOT; i += 64 * 256) {
            int idx = i;
            const void* src;
            u16 *dh, *dl;
            int K2, N2, nt, rem;
            if (idx < 36864) {
                nt = idx / 3072; rem = idx - nt * 3072; src = ca.src[16]; dh = c1h + idx; dl = c1l + idx; K2 = 192; N2 = 192;
            } else if (idx < 36864 + 3072) {
                idx -= 36864; nt = 0; rem = idx; src = ca.src[17]; dh = c2h + idx; dl = c2l + idx; K2 = 192; N2 = 3;
            } else if (idx < 36864 + 3072 + 65536) {
                idx -= 36864 + 3072; nt = idx / 4096; rem = idx - nt * 4096; src = ca.src[14]; dh = s1h + idx; dl = s1l + idx; K2 = 256; N2 = 256;
            } else {
                idx -= 36864 + 3072 + 65536; nt = 0; rem = idx; src = ca.src[15]; dh = s2h + idx; dl = s2l + idx; K2 = 256; N2 = 4;
            }
            int kb = rem >> 9, r8 = rem & 511, ln = r8 >> 3, j = r8 & 7;
            int k = kb * 32 + ((ln >> 4) << 3) + j;
            int n = nt * 16 + (ln & 15);
            float val = 0.f;
            if (n < N2 && k < K2) {
                int si = k * N2 + n;
                val = fl ? bfu(((const u16*)src)[si]) : ((const float*)src)[si];
            }
            u16 h = f2bf(val);
            *dh = h;
            *dl = f2bf(val - bfu(h));
        }
    } else {
        int base = (blockIdx.x - 65) * 256 + t;
        int stride = (gridDim.x - 65) * 256;
        for (int idx = base; idx < cvt_total; idx += stride) {
            int seg = 0, off = idx;
            while (off >= ca.cnt[seg]) { off -= ca.cnt[seg]; ++seg; }
            pool[idx] = cvtv(ca.src[seg], off, fl);
        }
    }
}

// ======== fused layer: projections + edge chain + node update, ping-pong x (NO aliasing) ========
// wave = (b,v). x_in is read-only this launch; x_out is written only at row v by its owner wave.
__global__ __launch_bounds__(256) void k_layer(
    const float* __restrict__ x_in, int Hin,
    const float* __restrict__ Wi, const float* __restrict__ Wj,
    const float* __restrict__ Vw, const float* __restrict__ U,
    const float* __restrict__ Ws, const float* __restrict__ ews,
    const int* __restrict__ row_ptr, const int* __restrict__ colp,
    const float* __restrict__ dinv,
    float* __restrict__ s_edge, float* __restrict__ x_out, int layer)
{
    int t = threadIdx.x, blk = blockIdx.x;
    int b = blk >> 4, vg = blk & 15;
    int wid = t >> 6, lane = t & 63;
    int v = (vg << 2) + wid;
    size_t rowb = (size_t)b << 6;

    int e0 = __builtin_amdgcn_readfirstlane(row_ptr[v]);
    int e1 = __builtin_amdgcn_readfirstlane(row_ptr[v + 1]);
    int nn = e1 - e0;

    float xrv = (Hin == 64) ? x_in[((rowb + v) << 6) + lane]
                            : (lane < 32 ? x_in[(rowb + v) * 32 + lane] : 0.f);

    int sflag[4];
    float xrw[4];
#pragma unroll
    for (int i = 0; i < 4; i++) {
        if (i < nn) {
            int cp = __builtin_amdgcn_readfirstlane(colp[e0 + i]);
            sflag[i] = (cp >> 8) & 1;
            int w = cp & 255;
            xrw[i] = (Hin == 64) ? x_in[((rowb + w) << 6) + lane]
                                 : (lane < 32 ? x_in[(rowb + w) * 32 + lane] : 0.f);
        } else { sflag[i] = 0; xrw[i] = 0.f; }
    }

    float wcol[64];
    float xiv, xuv, xjr[4], xvr[4];
    if (Hin == 64) {
#pragma unroll
        for (int h = 0; h < 64; h++) wcol[h] = Wi[h * 64 + lane];
        xiv = mv64(xrv, wcol);
#pragma unroll
        for (int h = 0; h < 64; h++) wcol[h] = U[h * 64 + lane];
        xuv = mv64(xrv, wcol);
#pragma unroll
        for (int h = 0; h < 64; h++) wcol[h] = Wj[h * 64 + lane];
#pragma unroll
        for (int i = 0; i < 4; i++) if (i < nn) xjr[i] = mv64(xrw[i], wcol);
#pragma unroll
        for (int h = 0; h < 64; h++) wcol[h] = Vw[h * 64 + lane];
#pragma unroll
        for (int i = 0; i < 4; i++) if (i < nn) xvr[i] = mv64(xrw[i], wcol);
    } else {
#pragma unroll
        for (int h = 0; h < 32; h++) wcol[h] = Wi[h * 64 + lane];
        xiv = mv32(xrv, wcol);
#pragma unroll
        for (int h = 0; h < 32; h++) wcol[h] = U[h * 64 + lane];
        xuv = mv32(xrv, wcol);
#pragma unroll
        for (int h = 0; h < 32; h++) wcol[h] = Wj[h * 64 + lane];
#pragma unroll
        for (int i = 0; i < 4; i++) if (i < nn) xjr[i] = mv32(xrw[i], wcol);
#pragma unroll
        for (int h = 0; h < 32; h++) wcol[h] = Vw[h * 64 + lane];
#pragma unroll
        for (int i = 0; i < 4; i++) if (i < nn) xvr[i] = mv32(xrw[i], wcol);
    }

    if (layer > 0) {
#pragma unroll
        for (int h = 0; h < 64; h++) wcol[h] = Ws[h * 64 + lane];
    }

    float acc = 0.f;
#pragma unroll
    for (int i = 0; i < 4; i++) {
        if (i < nn) {
            float* srow = s_edge + (((size_t)b * NE_MAX + e0 + i) << 6);
            float sout;
            if (layer == 0) {
                float ee = ews[(sflag[i] << 6) + lane] + xiv + xjr[i];
                sout = ln_relu64(ee);
            } else {
                float sp = srow[lane];
                float a = mv64(sp, wcol);
                sout = sp + ln_relu64(a + xiv + xjr[i]);
            }
            srow[lane] = sout;
            acc += xvr[i] / (1.f + __expf(-sout));
        }
    }

    size_t idx = ((rowb + v) << 6) + lane;
    float z = xuv + acc * dinv[v];
    float h = ln_relu64(z);
    x_out[idx] = (layer == 0) ? h : xrv + h;   // residual from register snapshot, no alias
}

// ======== fused heads (1024 threads: 16 waves tile-parallel) + xg + final ========
#define CSTR 204
#define SSTR 268
__global__ __launch_bounds__(1024) void k_heads(
    const float* __restrict__ s_edge, const int* __restrict__ sw_eidx,
    const int* __restrict__ eA, const int* __restrict__ eS,
    const float* __restrict__ x3,
    const u16* __restrict__ c1h, const u16* __restrict__ c1l,
    const u16* __restrict__ c2h, const u16* __restrict__ c2l,
    const u16* __restrict__ s1h, const u16* __restrict__ s1l,
    const u16* __restrict__ s2h, const u16* __restrict__ s2l,
    const float* __restrict__ dinvD, const int* __restrict__ incCnt, const int* __restrict__ incM,
    const u16* __restrict__ A_u16, void* __restrict__ out_v)
{
    __shared__ float hidF[64 * CSTR];     // 52.2 KB; smlp overlays 16 x SSTR
    __shared__ float xgL[64], xgP[1024];
    __shared__ float cmoL[EC * 3], smoL[NSW * 4];
    int b = blockIdx.x, t = threadIdx.x;
    int lane = t & 63, wid = t >> 6;      // wid 0..15
    int m = lane & 15, quad = lane >> 4;
    size_t rowb = (size_t)b << 6;
    int fl = (A_u16[1] == 0x3F80) ? 1 : 0;

    // ---- xg ----
    {
        float a = 0.f;
#pragma unroll
        for (int q = 0; q < 4; q++)
            a += x3[((rowb + (wid << 2) + q) << 6) + lane];
        xgP[wid * 64 + lane] = a;
    }
    __syncthreads();
    if (t < 64) {
        float s = 0.f;
#pragma unroll
        for (int i = 0; i < 16; i++) s += xgP[i * 64 + t];
        xgL[t] = s;
    }
    __syncthreads();

    // ---- cmlp GEMM1: tile (Mt, nt), Mt = wid>>2, nt in {wid&3, +4, +8} ----
    {
        int Mt = wid >> 2, ntb = wid & 3;
        int e = Mt * 16 + m; if (e > 62) e = 62;
        int ai = eA[e], aj = eA[EC + e];
        const float* seg0 = x3 + ((rowb + ai) << 6);
        const float* seg1 = x3 + ((rowb + aj) << 6);
        const float* seg2 = xgL;
        f32x4 acc[3];
#pragma unroll
        for (int j3 = 0; j3 < 3; j3++) acc[j3] = (f32x4){0.f, 0.f, 0.f, 0.f};
#pragma unroll
        for (int kb = 0; kb < 6; kb++) {
            int k = kb * 32 + quad * 8;
            const float* base = (k < 64) ? seg0 + k : (k < 128) ? seg1 + (k - 64) : seg2 + (k - 128);
            bf16x8 ah, al;
            split8(base, &ah, &al);
#pragma unroll
            for (int j3 = 0; j3 < 3; j3++) {
                int nt = ntb + j3 * 4;
                int o = ((nt * 6 + kb) << 9) + (lane << 3);
                bf16x8 bh = *(const bf16x8*)(c1h + o);
                bf16x8 bl = *(const bf16x8*)(c1l + o);
                acc[j3] = __builtin_amdgcn_mfma_f32_16x16x32_bf16(ah, bh, acc[j3], 0, 0, 0);
                acc[j3] = __builtin_amdgcn_mfma_f32_16x16x32_bf16(al, bh, acc[j3], 0, 0, 0);
                acc[j3] = __builtin_amdgcn_mfma_f32_16x16x32_bf16(ah, bl, acc[j3], 0, 0, 0);
            }
        }
#pragma unroll
        for (int j3 = 0; j3 < 3; j3++) {
            int nt = ntb + j3 * 4;
#pragma unroll
            for (int r = 0; r < 4; r++)
                hidF[(Mt * 16 + quad * 4 + r) * CSTR + nt * 16 + m] = fmaxf(acc[j3][r], 0.f);
        }
    }
    __syncthreads();

    // ---- cmlp GEMM2 (waves 0-3) ----
    if (wid < 4) {
        f32x4 accD = (f32x4){0.f, 0.f, 0.f, 0.f};
#pragma unroll
        for (int kb = 0; kb < 6; kb++) {
            bf16x8 ah, al;
            split8(&hidF[(wid * 16 + m) * CSTR + kb * 32 + quad * 8], &ah, &al);
            int o = (kb << 9) + (lane << 3);
            bf16x8 bh = *(const bf16x8*)(c2h + o);
            bf16x8 bl = *(const bf16x8*)(c2l + o);
            accD = __builtin_amdgcn_mfma_f32_16x16x32_bf16(ah, bh, accD, 0, 0, 0);
            accD = __builtin_amdgcn_mfma_f32_16x16x32_bf16(al, bh, accD, 0, 0, 0);
            accD = __builtin_amdgcn_mfma_f32_16x16x32_bf16(ah, bl, accD, 0, 0, 0);
        }
#pragma unroll
        for (int r = 0; r < 4; r++) {
            int row = wid * 16 + quad * 4 + r;
            if (row < EC && m < 3)
                cmoL[row * 3 + m] = 1.f / (1.f + __expf(-accD[r]));
        }
    }
    __syncthreads();

    // ---- smlp GEMM1: wave wid -> nt = wid ----
    {
        int e2 = (m > 9) ? 9 : m;
        int si = eS[e2], sj = eS[NSW + e2];
        int sw = sw_eidx[e2];
        const float* t0 = s_edge + (((size_t)b * NE_MAX + sw) << 6);
        const float* t1 = x3 + ((rowb + si) << 6);
        const float* t2 = x3 + ((rowb + sj) << 6);
        const float* t3 = xgL;
        f32x4 accS = (f32x4){0.f, 0.f, 0.f, 0.f};
#pragma unroll
        for (int kb = 0; kb < 8; kb++) {
            int k = kb * 32 + quad * 8;
            const float* base = (k < 64) ? t0 + k : (k < 128) ? t1 + (k - 64)
                              : (k < 192) ? t2 + (k - 128) : t3 + (k - 192);
            bf16x8 ah, al;
            split8(base, &ah, &al);
            int o = ((wid * 8 + kb) << 9) + (lane << 3);
            bf16x8 bh = *(const bf16x8*)(s1h + o);
            bf16x8 bl = *(const bf16x8*)(s1l + o);
            accS = __builtin_amdgcn_mfma_f32_16x16x32_bf16(ah, bh, accS, 0, 0, 0);
            accS = __builtin_amdgcn_mfma_f32_16x16x32_bf16(al, bh, accS, 0, 0, 0);
            accS = __builtin_amdgcn_mfma_f32_16x16x32_bf16(ah, bl, accS, 0, 0, 0);
        }
#pragma unroll
        for (int r = 0; r < 4; r++)
            hidF[(quad * 4 + r) * SSTR + wid * 16 + m] = fmaxf(accS[r], 0.f);
    }
    __syncthreads();

    // ---- smlp GEMM2 (wave 0) ----
    if (wid == 0) {
        f32x4 accT = (f32x4){0.f, 0.f, 0.f, 0.f};
#pragma unroll
        for (int kb = 0; kb < 8; kb++) {
            bf16x8 ah, al;
            split8(&hidF[m * SSTR + kb * 32 + quad * 8], &ah, &al);
            int o = (kb << 9) + (lane << 3);
            bf16x8 bh = *(const bf16x8*)(s2h + o);
            bf16x8 bl = *(const bf16x8*)(s2l + o);
            accT = __builtin_amdgcn_mfma_f32_16x16x32_bf16(ah, bh, accT, 0, 0, 0);
            accT = __builtin_amdgcn_mfma_f32_16x16x32_bf16(al, bh, accT, 0, 0, 0);
            accT = __builtin_amdgcn_mfma_f32_16x16x32_bf16(ah, bl, accT, 0, 0, 0);
        }
#pragma unroll
        for (int r = 0; r < 4; r++) {
            int row = quad * 4 + r;
            if (row < NSW && m < 4)
                smoL[row * 4 + m] = 1.f / (1.f + __expf(-accT[r]));
        }
    }
    __syncthreads();

    // ---- final assembly ----
    if (t < 2 * MNE + VN) {
        float val;
        if (t < MNE) {
            val = (t < EC) ? cmoL[t * 3] - 0.5f : smoL[(t - EC) * 4 + 1] - 0.5f;
        } else if (t < MNE + VN) {
            int i = t - MNE;
            if (i == 0) {
                val = 1.0f;
            } else {
                float acc = 0.f;
                int c = incCnt[i];
                for (int q = 0; q < c; q++) {
                    int em = incM[i * 8 + q];
                    int mm = em >> 1, role = em & 1;
                    float vv = (mm < EC) ? 0.9f + 0.2f * cmoL[mm * 3 + 1 + role]
                                         : 0.9f + 0.2f * smoL[(mm - EC) * 4 + 2 + role];
                    acc += vv;
                }
                val = acc * dinvD[i];
            }
        } else {
            int mm = t - (MNE + VN);
            val = (mm < EC) ? 1.0f : smoL[(mm - EC) * 4];
        }
        size_t oidx = (size_t)b * (2 * MNE + VN) + t;
        if (fl) ((u16*)out_v)[oidx] = f2bf(val);
        else    ((float*)out_v)[oidx] = val;
    }
}

extern "C" void kernel_launch(void* const* d_in, const int* in_sizes, int n_in,
                              void* d_out, int out_size, void* d_ws, size_t ws_size,
                              hipStream_t stream) {
    const int* eA = (const int*)d_in[21];
    const int* eS = (const int*)d_in[22];

    float* pool = (float*)d_ws;

    int off[22];
    off[0] = 0;
    for (int i = 0; i < 21; i++) off[i + 1] = off[i] + in_sizes[i];
    int cvt_total = off[21];

    const float* P_x    = pool + off[0];
    const float* P_p0Wi = pool + off[5];
    const float* P_p0Wj = pool + off[6];
    const float* P_p0U  = pool + off[7];
    const float* P_p0V  = pool + off[8];
    const float* P_plWs = pool + off[9];
    const float* P_plWi = pool + off[10];
    const float* P_plWj = pool + off[11];
    const float* P_plU  = pool + off[12];
    const float* P_plV  = pool + off[13];

    const int NR = BN * VN * HIDD;           // 819,200
    float* tail = pool + ((cvt_total + 7) & ~7);
    float* xA     = tail;
    float* xB     = xA + NR;
    float* s_edge = xB + NR;                 // 200*256*64 floats
    float* dinv   = s_edge + (size_t)BN * NE_MAX * 64;
    float* ews    = dinv + 64;
    u16*   c1h  = (u16*)(ews + 128);
    u16*   c1l  = c1h + 36864;
    u16*   c2h  = c1l + 36864;
    u16*   c2l  = c2h + 3072;
    u16*   s1h  = c2l + 3072;
    u16*   s1l  = s1h + 65536;
    u16*   s2h  = s1l + 65536;
    u16*   s2l  = s2h + 4096;
    int*   row_ptr = (int*)(s2l + 4096);
    int*   colp    = row_ptr + 80;
    int*   sw_eidx = colp + NE_MAX;
    float* dinvD   = (float*)(sw_eidx + 16);
    int*   incCnt  = (int*)(dinvD + 64);
    int*   incM    = incCnt + 64;

    CvtArgs ca;
    for (int i = 0; i < 21; i++) { ca.src[i] = d_in[i]; ca.cnt[i] = in_sizes[i]; }

    int cvB = (cvt_total + 255) / 256;
    k_prep<<<65 + cvB, 256, 0, stream>>>(ca, eA, eS, pool,
                                         c1h, c1l, c2h, c2l, s1h, s1l, s2h, s2l,
                                         ews, dinv, row_ptr, colp, sw_eidx,
                                         dinvD, incCnt, incM, cvt_total);

    // ping-pong: P_x -> xA -> xB -> xA  (x_in never aliases x_out)
    k_layer<<<BN * 16, 256, 0, stream>>>(P_x, FINN, P_p0Wi, P_p0Wj, P_p0V, P_p0U,
                                         P_plWs, ews, row_ptr, colp, dinv, s_edge, xA, 0);
    k_layer<<<BN * 16, 256, 0, stream>>>(xA, HIDD, P_plWi, P_plWj, P_plV, P_plU,
                                         P_plWs, ews, row_ptr, colp, dinv, s_edge, xB, 1);
    k_layer<<<BN * 16, 256, 0, stream>>>(xB, HIDD, P_plWi + 4096, P_plWj + 4096,
                                         P_plV + 4096, P_plU + 4096,
                                         P_plWs + 4096, ews, row_ptr, colp, dinv, s_edge, xA, 2);

    k_heads<<<BN, 1024, 0, stream>>>(s_edge, sw_eidx, eA, eS, xA,
                                     c1h, c1l, c2h, c2l, s1h, s1l, s2h, s2l,
                                     dinvD, incCnt, incM, (const u16*)d_in[1], d_out);
}

// Round 15
// 290.605 us; speedup vs baseline: 1.4111x; 1.4111x over previous
//
#include <hip/hip_runtime.h>

#define BN 200
#define VN 64
#define HIDD 64
#define FINN 32
#define NSW 10
#define EC 63
#define MNE 73
#define NE_MAX 256

typedef unsigned short u16;
typedef unsigned int u32;
typedef __attribute__((ext_vector_type(8))) short bf16x8;
typedef __attribute__((ext_vector_type(4))) float f32x4;

__device__ __forceinline__ float bfu(u16 u) { return __uint_as_float(((u32)u) << 16); }
__device__ __forceinline__ u16 f2bf(float f) {
    u32 x = __float_as_uint(f);
    u32 r = x + 0x7fffu + ((x >> 16) & 1u);
    return (u16)(r >> 16);
}
__device__ __forceinline__ float cvtv(const void* p, int i, int fl) {
    return fl ? bfu(((const u16*)p)[i]) : ((const float*)p)[i];
}
__device__ __forceinline__ float rlane(float v, int h) {
    return __uint_as_float(__builtin_amdgcn_readlane(__float_as_uint(v), h));
}

__device__ __forceinline__ float ln_relu64(float e) {
    float s1 = e, s2 = e * e;
#pragma unroll
    for (int m = 1; m < 64; m <<= 1) {
        s1 += __shfl_xor(s1, m);
        s2 += __shfl_xor(s2, m);
    }
    float mean = s1 * 0.015625f;
    float var = fmaxf(s2 * 0.015625f - mean * mean, 0.f);
    return fmaxf((e - mean) * rsqrtf(var + 1e-5f), 0.f);
}

// split 8 consecutive floats into hi/lo bf16 fragments
__device__ __forceinline__ void split8(const float* base, bf16x8* hi, bf16x8* lo) {
    union { bf16x8 v; u16 s[8]; } uh, ul;
#pragma unroll
    for (int j = 0; j < 8; j++) {
        float f = base[j];
        u16 h = f2bf(f);
        uh.s[j] = h;
        ul.s[j] = f2bf(f - bfu(h));
    }
    *hi = uh.v;
    *lo = ul.v;
}

struct CvtArgs {
    const void* src[21];
    int cnt[21];
};

// ======== prep: block 0 = CSR/ews/dinv/sw_eidx/inc-lists; blocks 1-64 = head pack; rest = convert ========
__global__ __launch_bounds__(256) void k_prep(CvtArgs ca, const int* __restrict__ eA,
                                              const int* __restrict__ eS,
                                              float* __restrict__ pool,
                                              u16* __restrict__ c1h, u16* __restrict__ c1l,
                                              u16* __restrict__ c2h, u16* __restrict__ c2l,
                                              u16* __restrict__ s1h, u16* __restrict__ s1l,
                                              u16* __restrict__ s2h, u16* __restrict__ s2l,
                                              float* __restrict__ ews, float* __restrict__ dinv,
                                              int* __restrict__ row_ptr, int* __restrict__ colp,
                                              int* __restrict__ sw_eidx,
                                              float* __restrict__ dinvD, int* __restrict__ incCnt,
                                              int* __restrict__ incM, int cvt_total) {
    int t = threadIdx.x;
    int fl = (((const u16*)ca.src[1])[1] == 0x3F80) ? 1 : 0;
    if (blockIdx.x == 0) {
        __shared__ float connL[4096];
        __shared__ int degL[64], rpS[65];
        const void* A = ca.src[1];
        const void* S = ca.src[2];
        for (int i = t; i < 4096; i += 256)
            connL[i] = fminf(cvtv(A, i, fl) + cvtv(S, i, fl), 1.f);
        if (t < 128) {
            int j = t >> 6, k = t & 63;
            float a = 0.f;
            for (int h = 0; h < FINN; h++)
                a += cvtv(ca.src[3], j * FINN + h, fl) * cvtv(ca.src[4], h * 64 + k, fl);
            ews[(j << 6) + k] = a;
        }
        __syncthreads();
        if (t < 64) {
            int d = 0;
            for (int w = 0; w < 64; w++) if (connL[t * 64 + w] != 0.f) d++;
            degL[t] = d;
            dinv[t] = 1.f / fmaxf((float)d, 1.f);
        }
        __syncthreads();
        if (t == 0) {
            int c = 0;
            for (int v = 0; v < 64; v++) { rpS[v] = c; c += degL[v]; }
            rpS[64] = c;
            for (int v = 0; v <= 64; v++) row_ptr[v] = rpS[v];
        }
        __syncthreads();
        if (t < 64) {
            int pos = rpS[t];
            for (int w = 0; w < 64; w++)
                if (connL[t * 64 + w] != 0.f)
                    colp[pos++] = w | ((cvtv(S, t * 64 + w, fl) != 0.f) ? 256 : 0);
        }
        __syncthreads();
        if (t < NSW) {
            int si = eS[t], sj = eS[NSW + t];
            int idx = 0;
            for (int e = rpS[si]; e < rpS[si + 1]; e++)
                if ((colp[e] & 255) == sj) idx = e;
            sw_eidx[t] = idx;
        }
        if (t < 64) {
            dinvD[t] = cvtv(ca.src[18], t * 64 + t, fl);
            int cnt = 0;
            for (int m = 0; m < MNE; m++) {
                int par = (m < EC) ? eA[m] : eS[m - EC];
                int chi = (m < EC) ? eA[EC + m] : eS[NSW + (m - EC)];
                if (par == t && cnt < 8) incM[t * 8 + cnt++] = (m << 1);
                if (chi == t && cnt < 8) incM[t * 8 + cnt++] = (m << 1) | 1;
            }
            incCnt[t] = cnt;
        }
    } else if (blockIdx.x <= 64) {
        const int TOT = 36864 + 3072 + 65536 + 4096;
        for (int i = (blockIdx.x - 1) * 256 + t; i < TOT; i += 64 * 256) {
            int idx = i;
            const void* src;
            u16 *dh, *dl;
            int K2, N2, nt, rem;
            if (idx < 36864) {
                nt = idx / 3072; rem = idx - nt * 3072; src = ca.src[16]; dh = c1h + idx; dl = c1l + idx; K2 = 192; N2 = 192;
            } else if (idx < 36864 + 3072) {
                idx -= 36864; nt = 0; rem = idx; src = ca.src[17]; dh = c2h + idx; dl = c2l + idx; K2 = 192; N2 = 3;
            } else if (idx < 36864 + 3072 + 65536) {
                idx -= 36864 + 3072; nt = idx / 4096; rem = idx - nt * 4096; src = ca.src[14]; dh = s1h + idx; dl = s1l + idx; K2 = 256; N2 = 256;
            } else {
                idx -= 36864 + 3072 + 65536; nt = 0; rem = idx; src = ca.src[15]; dh = s2h + idx; dl = s2l + idx; K2 = 256; N2 = 4;
            }
            int kb = rem >> 9, r8 = rem & 511, ln = r8 >> 3, j = r8 & 7;
            int k = kb * 32 + ((ln >> 4) << 3) + j;
            int n = nt * 16 + (ln & 15);
            float val = 0.f;
            if (n < N2 && k < K2) {
                int si = k * N2 + n;
                val = fl ? bfu(((const u16*)src)[si]) : ((const float*)src)[si];
            }
            u16 h = f2bf(val);
            *dh = h;
            *dl = f2bf(val - bfu(h));
        }
    } else {
        int base = (blockIdx.x - 65) * 256 + t;
        int stride = (gridDim.x - 65) * 256;
        for (int idx = base; idx < cvt_total; idx += stride) {
            int seg = 0, off = idx;
            while (off >= ca.cnt[seg]) { off -= ca.cnt[seg]; ++seg; }
            pool[idx] = cvtv(ca.src[seg], off, fl);
        }
    }
}

// -------- node transforms, 16 rows/block, readlane broadcasts --------
__global__ __launch_bounds__(256) void k_xw(const float* __restrict__ x, int Hin,
                                            const float* __restrict__ Wi, const float* __restrict__ Wj,
                                            const float* __restrict__ Vw, const float* __restrict__ U,
                                            float* __restrict__ xi, float* __restrict__ xj,
                                            float* __restrict__ xv, float* __restrict__ xu) {
    int t = threadIdx.x, lane = t & 63, wid = t >> 6;
    size_t row0 = (size_t)blockIdx.x * 16;
    const float* W = (wid == 0) ? Wi : (wid == 1) ? Wj : (wid == 2) ? Vw : U;
    float* out = (wid == 0) ? xi : (wid == 1) ? xj : (wid == 2) ? xv : xu;

    float xd[16];
#pragma unroll
    for (int r = 0; r < 16; r++)
        xd[r] = (Hin == 64) ? x[(row0 + r) * 64 + lane]
                            : (lane < 32 ? x[(row0 + r) * 32 + lane] : 0.f);
    float acc[16];
#pragma unroll
    for (int r = 0; r < 16; r++) acc[r] = 0.f;
    for (int h = 0; h < Hin; h++) {
        float wv = W[h * 64 + lane];
#pragma unroll
        for (int r = 0; r < 16; r++) acc[r] += rlane(xd[r], h) * wv;
    }
#pragma unroll
    for (int r = 0; r < 16; r++) out[(row0 + r) * 64 + lane] = acc[r];
}

// -------- sparse edge kernel + fused node update (readlane matvec) --------
__global__ __launch_bounds__(256) void k_edge(
    const float* __restrict__ ews, const float* __restrict__ Ws,
    const int* __restrict__ row_ptr, const int* __restrict__ colp,
    const float* __restrict__ dinv,
    const float* __restrict__ xi, const float* __restrict__ xj,
    const float* __restrict__ xv, const float* __restrict__ xu,
    float* __restrict__ s_edge, float* __restrict__ x_cur, int layer)
{
    int t = threadIdx.x, blk = blockIdx.x;
    int b = blk >> 4, vg = blk & 15;
    int wid = t >> 6, lane = t & 63;
    int v = (vg << 2) + wid;
    size_t rowb = (size_t)b << 6;

    float wreg[64];
    if (layer > 0) {
#pragma unroll
        for (int h = 0; h < 64; h++) wreg[h] = Ws[h * 64 + lane];
    }

    int e0 = __builtin_amdgcn_readfirstlane(row_ptr[v]);
    int e1 = __builtin_amdgcn_readfirstlane(row_ptr[v + 1]);
    float xival = xi[((rowb + v) << 6) + lane];
    float acc = 0.f;

    for (int e = e0; e < e1; e++) {
        int cp = __builtin_amdgcn_readfirstlane(colp[e]);
        int w = cp & 255;
        float xjv = xj[((rowb + w) << 6) + lane];
        float* srow = s_edge + (((size_t)b * NE_MAX + e) << 6);
        float sout;
        if (layer == 0) {
            int sidx = (cp >> 8) & 1;
            float ee = ews[(sidx << 6) + lane] + xival + xjv;
            sout = ln_relu64(ee);
        } else {
            float sp = srow[lane];
            float a = 0.f;
#pragma unroll
            for (int h = 0; h < 64; h++) a += rlane(sp, h) * wreg[h];
            float ee = a + xival + xjv;
            sout = sp + ln_relu64(ee);
        }
        srow[lane] = sout;
        acc += xv[((rowb + w) << 6) + lane] / (1.f + __expf(-sout));
    }
    float mval = acc * dinv[v];

    size_t idx = ((rowb + v) << 6) + lane;
    float z = xu[idx] + mval;
    float h = ln_relu64(z);
    if (layer == 0) x_cur[idx] = h;
    else            x_cur[idx] = x_cur[idx] + h;
}

// ======== fused heads (1024 threads: 16 waves tile-parallel) + xg + final ========
#define CSTR 204
#define SSTR 268
__global__ __launch_bounds__(1024) void k_heads(
    const float* __restrict__ s_edge, const int* __restrict__ sw_eidx,
    const int* __restrict__ eA, const int* __restrict__ eS,
    const float* __restrict__ x3,
    const u16* __restrict__ c1h, const u16* __restrict__ c1l,
    const u16* __restrict__ c2h, const u16* __restrict__ c2l,
    const u16* __restrict__ s1h, const u16* __restrict__ s1l,
    const u16* __restrict__ s2h, const u16* __restrict__ s2l,
    const float* __restrict__ dinvD, const int* __restrict__ incCnt, const int* __restrict__ incM,
    const u16* __restrict__ A_u16, void* __restrict__ out_v)
{
    __shared__ float hidF[64 * CSTR];     // 52.2 KB; smlp overlays 16 x SSTR
    __shared__ float xgL[64], xgP[1024];
    __shared__ float cmoL[EC * 3], smoL[NSW * 4];
    int b = blockIdx.x, t = threadIdx.x;
    int lane = t & 63, wid = t >> 6;      // wid 0..15
    int m = lane & 15, quad = lane >> 4;
    size_t rowb = (size_t)b << 6;
    int fl = (A_u16[1] == 0x3F80) ? 1 : 0;

    // ---- xg ----
    {
        float a = 0.f;
#pragma unroll
        for (int q = 0; q < 4; q++)
            a += x3[((rowb + (wid << 2) + q) << 6) + lane];
        xgP[wid * 64 + lane] = a;
    }
    __syncthreads();
    if (t < 64) {
        float s = 0.f;
#pragma unroll
        for (int i = 0; i < 16; i++) s += xgP[i * 64 + t];
        xgL[t] = s;
    }
    __syncthreads();

    // ---- cmlp GEMM1: tile (Mt, nt), Mt = wid>>2, nt in {wid&3, +4, +8} ----
    {
        int Mt = wid >> 2, ntb = wid & 3;
        int e = Mt * 16 + m; if (e > 62) e = 62;
        int ai = eA[e], aj = eA[EC + e];
        const float* seg0 = x3 + ((rowb + ai) << 6);
        const float* seg1 = x3 + ((rowb + aj) << 6);
        const float* seg2 = xgL;
        f32x4 acc[3];
#pragma unroll
        for (int j3 = 0; j3 < 3; j3++) acc[j3] = (f32x4){0.f, 0.f, 0.f, 0.f};
#pragma unroll
        for (int kb = 0; kb < 6; kb++) {
            int k = kb * 32 + quad * 8;
            const float* base = (k < 64) ? seg0 + k : (k < 128) ? seg1 + (k - 64) : seg2 + (k - 128);
            bf16x8 ah, al;
            split8(base, &ah, &al);
#pragma unroll
            for (int j3 = 0; j3 < 3; j3++) {
                int nt = ntb + j3 * 4;
                int o = ((nt * 6 + kb) << 9) + (lane << 3);
                bf16x8 bh = *(const bf16x8*)(c1h + o);
                bf16x8 bl = *(const bf16x8*)(c1l + o);
                acc[j3] = __builtin_amdgcn_mfma_f32_16x16x32_bf16(ah, bh, acc[j3], 0, 0, 0);
                acc[j3] = __builtin_amdgcn_mfma_f32_16x16x32_bf16(al, bh, acc[j3], 0, 0, 0);
                acc[j3] = __builtin_amdgcn_mfma_f32_16x16x32_bf16(ah, bl, acc[j3], 0, 0, 0);
            }
        }
#pragma unroll
        for (int j3 = 0; j3 < 3; j3++) {
            int nt = ntb + j3 * 4;
#pragma unroll
            for (int r = 0; r < 4; r++)
                hidF[(Mt * 16 + quad * 4 + r) * CSTR + nt * 16 + m] = fmaxf(acc[j3][r], 0.f);
        }
    }
    __syncthreads();

    // ---- cmlp GEMM2 (waves 0-3) ----
    if (wid < 4) {
        f32x4 accD = (f32x4){0.f, 0.f, 0.f, 0.f};
#pragma unroll
        for (int kb = 0; kb < 6; kb++) {
            bf16x8 ah, al;
            split8(&hidF[(wid * 16 + m) * CSTR + kb * 32 + quad * 8], &ah, &al);
            int o = (kb << 9) + (lane << 3);
            bf16x8 bh = *(const bf16x8*)(c2h + o);
            bf16x8 bl = *(const bf16x8*)(c2l + o);
            accD = __builtin_amdgcn_mfma_f32_16x16x32_bf16(ah, bh, accD, 0, 0, 0);
            accD = __builtin_amdgcn_mfma_f32_16x16x32_bf16(al, bh, accD, 0, 0, 0);
            accD = __builtin_amdgcn_mfma_f32_16x16x32_bf16(ah, bl, accD, 0, 0, 0);
        }
#pragma unroll
        for (int r = 0; r < 4; r++) {
            int row = wid * 16 + quad * 4 + r;
            if (row < EC && m < 3)
                cmoL[row * 3 + m] = 1.f / (1.f + __expf(-accD[r]));
        }
    }
    __syncthreads();

    // ---- smlp GEMM1: wave wid -> nt = wid ----
    {
        int e2 = (m > 9) ? 9 : m;
        int si = eS[e2], sj = eS[NSW + e2];
        int sw = sw_eidx[e2];
        const float* t0 = s_edge + (((size_t)b * NE_MAX + sw) << 6);
        const float* t1 = x3 + ((rowb + si) << 6);
        const float* t2 = x3 + ((rowb + sj) << 6);
        const float* t3 = xgL;
        f32x4 accS = (f32x4){0.f, 0.f, 0.f, 0.f};
#pragma unroll
        for (int kb = 0; kb < 8; kb++) {
            int k = kb * 32 + quad * 8;
            const float* base = (k < 64) ? t0 + k : (k < 128) ? t1 + (k - 64)
                              : (k < 192) ? t2 + (k - 128) : t3 + (k - 192);
            bf16x8 ah, al;
            split8(base, &ah, &al);
            int o = ((wid * 8 + kb) << 9) + (lane << 3);
            bf16x8 bh = *(const bf16x8*)(s1h + o);
            bf16x8 bl = *(const bf16x8*)(s1l + o);
            accS = __builtin_amdgcn_mfma_f32_16x16x32_bf16(ah, bh, accS, 0, 0, 0);
            accS = __builtin_amdgcn_mfma_f32_16x16x32_bf16(al, bh, accS, 0, 0, 0);
            accS = __builtin_amdgcn_mfma_f32_16x16x32_bf16(ah, bl, accS, 0, 0, 0);
        }
#pragma unroll
        for (int r = 0; r < 4; r++)
            hidF[(quad * 4 + r) * SSTR + wid * 16 + m] = fmaxf(accS[r], 0.f);
    }
    __syncthreads();

    // ---- smlp GEMM2 (wave 0) ----
    if (wid == 0) {
        f32x4 accT = (f32x4){0.f, 0.f, 0.f, 0.f};
#pragma unroll
        for (int kb = 0; kb < 8; kb++) {
            bf16x8 ah, al;
            split8(&hidF[m * SSTR + kb * 32 + quad * 8], &ah, &al);
            int o = (kb << 9) + (lane << 3);
            bf16x8 bh = *(const bf16x8*)(s2h + o);
            bf16x8 bl = *(const bf16x8*)(s2l + o);
            accT = __builtin_amdgcn_mfma_f32_16x16x32_bf16(ah, bh, accT, 0, 0, 0);
            accT = __builtin_amdgcn_mfma_f32_16x16x32_bf16(al, bh, accT, 0, 0, 0);
            accT = __builtin_amdgcn_mfma_f32_16x16x32_bf16(ah, bl, accT, 0, 0, 0);
        }
#pragma unroll
        for (int r = 0; r < 4; r++) {
            int row = quad * 4 + r;
            if (row < NSW && m < 4)
                smoL[row * 4 + m] = 1.f / (1.f + __expf(-accT[r]));
        }
    }
    __syncthreads();

    // ---- final assembly ----
    if (t < 2 * MNE + VN) {
        float val;
        if (t < MNE) {
            val = (t < EC) ? cmoL[t * 3] - 0.5f : smoL[(t - EC) * 4 + 1] - 0.5f;
        } else if (t < MNE + VN) {
            int i = t - MNE;
            if (i == 0) {
                val = 1.0f;
            } else {
                float acc = 0.f;
                int c = incCnt[i];
                for (int q = 0; q < c; q++) {
                    int em = incM[i * 8 + q];
                    int mm = em >> 1, role = em & 1;
                    float vv = (mm < EC) ? 0.9f + 0.2f * cmoL[mm * 3 + 1 + role]
                                         : 0.9f + 0.2f * smoL[(mm - EC) * 4 + 2 + role];
                    acc += vv;
                }
                val = acc * dinvD[i];
            }
        } else {
            int mm = t - (MNE + VN);
            val = (mm < EC) ? 1.0f : smoL[(mm - EC) * 4];
        }
        size_t oidx = (size_t)b * (2 * MNE + VN) + t;
        if (fl) ((u16*)out_v)[oidx] = f2bf(val);
        else    ((float*)out_v)[oidx] = val;
    }
}

extern "C" void kernel_launch(void* const* d_in, const int* in_sizes, int n_in,
                              void* d_out, int out_size, void* d_ws, size_t ws_size,
                              hipStream_t stream) {
    const int* eA = (const int*)d_in[21];
    const int* eS = (const int*)d_in[22];

    float* pool = (float*)d_ws;

    int off[22];
    off[0] = 0;
    for (int i = 0; i < 21; i++) off[i + 1] = off[i] + in_sizes[i];
    int cvt_total = off[21];

    const float* P_x    = pool + off[0];
    const float* P_p0Wi = pool + off[5];
    const float* P_p0Wj = pool + off[6];
    const float* P_p0U  = pool + off[7];
    const float* P_p0V  = pool + off[8];
    const float* P_plWs = pool + off[9];
    const float* P_plWi = pool + off[10];
    const float* P_plWj = pool + off[11];
    const float* P_plU  = pool + off[12];
    const float* P_plV  = pool + off[13];

    const int NR = BN * VN * HIDD;           // 819,200
    float* tail = pool + ((cvt_total + 7) & ~7);
    float* xi    = tail;
    float* xj    = xi + NR;
    float* xv    = xj + NR;
    float* xu    = xv + NR;
    float* x_cur = xu + NR;
    float* s_edge = x_cur + NR;              // 200*256*64 floats
    float* dinv   = s_edge + (size_t)BN * NE_MAX * 64;
    float* ews    = dinv + 64;
    u16*   c1h  = (u16*)(ews + 128);
    u16*   c1l  = c1h + 36864;
    u16*   c2h  = c1l + 36864;
    u16*   c2l  = c2h + 3072;
    u16*   s1h  = c2l + 3072;
    u16*   s1l  = s1h + 65536;
    u16*   s2h  = s1l + 65536;
    u16*   s2l  = s2h + 4096;
    int*   row_ptr = (int*)(s2l + 4096);
    int*   colp    = row_ptr + 80;
    int*   sw_eidx = colp + NE_MAX;
    float* dinvD   = (float*)(sw_eidx + 16);
    int*   incCnt  = (int*)(dinvD + 64);
    int*   incM    = incCnt + 64;

    CvtArgs ca;
    for (int i = 0; i < 21; i++) { ca.src[i] = d_in[i]; ca.cnt[i] = in_sizes[i]; }

    int cvB = (cvt_total + 255) / 256;
    k_prep<<<65 + cvB, 256, 0, stream>>>(ca, eA, eS, pool,
                                         c1h, c1l, c2h, c2l, s1h, s1l, s2h, s2l,
                                         ews, dinv, row_ptr, colp, sw_eidx,
                                         dinvD, incCnt, incM, cvt_total);

    // layer 0
    k_xw<<<BN * VN / 16, 256, 0, stream>>>(P_x, FINN, P_p0Wi, P_p0Wj, P_p0V, P_p0U, xi, xj, xv, xu);
    k_edge<<<BN * 16, 256, 0, stream>>>(ews, P_plWs, row_ptr, colp, dinv, xi, xj, xv, xu,
                                        s_edge, x_cur, 0);
    // layer 1
    k_xw<<<BN * VN / 16, 256, 0, stream>>>(x_cur, HIDD, P_plWi, P_plWj, P_plV, P_plU, xi, xj, xv, xu);
    k_edge<<<BN * 16, 256, 0, stream>>>(ews, P_plWs, row_ptr, colp, dinv, xi, xj, xv, xu,
                                        s_edge, x_cur, 1);
    // layer 2
    k_xw<<<BN * VN / 16, 256, 0, stream>>>(x_cur, HIDD, P_plWi + 4096, P_plWj + 4096,
                                           P_plV + 4096, P_plU + 4096, xi, xj, xv, xu);
    k_edge<<<BN * 16, 256, 0, stream>>>(ews, P_plWs + 4096, row_ptr, colp, dinv, xi, xj, xv, xu,
                                        s_edge, x_cur, 2);

    k_heads<<<BN, 1024, 0, stream>>>(s_edge, sw_eidx, eA, eS, x_cur,
                                     c1h, c1l, c2h, c2l, s1h, s1l, s2h, s2l,
                                     dinvD, incCnt, incM, (const u16*)d_in[1], d_out);
}